// Round 14
// baseline (99.870 us; speedup 1.0000x reference)
//
#include <hip/hip_runtime.h>

// PointSIFT: octant-wise nearest neighbor within radius + group.
// B=2, N=4096, C=64 fixed; xyz uniform in [0,1)^3, radius=0.25.
//
// Two-kernel design:
//   1. build_grid: counting-sort points into a 4x4x4 cell grid (cell width
//      0.25 = radius). Sorted float4 = (x,y,z, orig_idx bits) in d_ws.
//   2. select_gather: ONE WAVE PER 2 CONSECUTIVE SORTED QUERIES (shared
//      candidate box = union of the two per-query boxes; sorted-adjacent
//      queries nearly share a box, so each candidate LOAD serves 2 queries).
//      Scoreboard = 2x8 u64 slots per wave in LDS, updated with predicated
//      fire-and-forget ds_min_u64 (only lanes with dist < judge issue it).
//      Lexicographic u64 min of (key<<32|idx) == reference first-min +
//      original-index tie-break, scan-order-independent. Winners read back
//      from the wave's LDS slots (same-wave DS ordering is in-order);
//      gather fused in the epilogue.
//
// Packed key: hi = float_bits(dist) - (float_bits(1e-10f)+1)
//   - dist <= 1e-10 (incl. self) wraps to huge -> loses to the seed
//   - dist >= judge never issues the atomic (strict-< exact)
//   - valid dists monotone; ties on key fall to min orig idx = ref tie-break
#define BB 2
#define NN 4096
#define CC 64
#define QPW 2               // queries per wave (shared scan)
#define NT 256              // threads per select block (4 waves)

// flat output layout (all float32):
//   out0 grouped_xyz   [B,N,8,3]
//   out1 grouped_points[B,N,8,67]
//   out2 idx (as float)[B,N,8]
#define OUT0_OFF 0
#define OUT1_OFF (BB * NN * 8 * 3)               /* 196608 */
#define OUT2_OFF (OUT1_OFF + BB * NN * 8 * 67)   /* 4587520 */

// d_ws layout: sorted float4 [B*NN], then offsets int [B*65]
#define WS_SORTED_BYTES (BB * NN * 16)

__global__ __launch_bounds__(1024) void build_grid(
    const float* __restrict__ xyz, float4* __restrict__ sorted,
    int* __restrict__ offsets)
{
    __shared__ int hist[64];
    __shared__ int offs[65];
    const int b = blockIdx.x;
    const int tid = threadIdx.x;
    if (tid < 64) hist[tid] = 0;
    __syncthreads();
    const float* src = xyz + (size_t)b * NN * 3;
    #pragma unroll
    for (int p = tid; p < NN; p += 1024) {
        float x = src[p * 3 + 0], y = src[p * 3 + 1], z = src[p * 3 + 2];
        int cell = (((int)(x * 4.0f)) << 4) | (((int)(y * 4.0f)) << 2)
                 | ((int)(z * 4.0f));            // x in [0,1) -> cell in [0,64)
        atomicAdd(&hist[cell], 1);
    }
    __syncthreads();
    if (tid < 64) {                              // wave 0: shfl prefix scan
        int inc = hist[tid];
        #pragma unroll
        for (int d = 1; d < 64; d <<= 1) {
            int u = __shfl_up(inc, d, 64);
            if (tid >= d) inc += u;
        }
        offs[tid + 1] = inc;                     // inclusive -> offs[1..64]
        if (tid == 0) offs[0] = 0;
    }
    __syncthreads();
    if (tid < 65) offsets[b * 65 + tid] = offs[tid];
    if (tid < 64) hist[tid] = offs[tid];         // reuse as scatter cursors
    __syncthreads();
    float4* dst = sorted + (size_t)b * NN;
    #pragma unroll
    for (int p = tid; p < NN; p += 1024) {
        float x = src[p * 3 + 0], y = src[p * 3 + 1], z = src[p * 3 + 2];
        int cell = (((int)(x * 4.0f)) << 4) | (((int)(y * 4.0f)) << 2)
                 | ((int)(z * 4.0f));
        int pos = atomicAdd(&hist[cell], 1);     // order within cell arbitrary
        dst[pos] = make_float4(x, y, z, __uint_as_float((unsigned)p));
    }
}

__global__ __launch_bounds__(NT, 4) void select_gather(
    const float4* __restrict__ sorted, const int* __restrict__ offsets,
    const float* __restrict__ xyz, const float* __restrict__ points,
    const float* __restrict__ radius_p, float* __restrict__ out)
{
    __shared__ int s_off[65];
    __shared__ unsigned long long s_sb[4 * QPW * 8];  // 8 slots per (wave,query)

    const int tid = threadIdx.x;
    const int blk = blockIdx.x;
    const int b = blk >> 9;                      // 512 blocks per batch
    const int wid = tid >> 6;                    // wave id 0..3
    const int sub = tid & 63;
    const int qslot = ((blk & 511) * 4 + wid) * QPW;  // sorted-array slot base
    const float4* sb = sorted + (size_t)b * NN;

    if (tid < 65) s_off[tid] = offsets[b * 65 + tid];

    const float r = radius_p[0];
    const float judge = __fmul_rn(r, r);
    const unsigned OFFC = __float_as_uint(1e-10f) + 1u;   // wrap offset
    const unsigned seedkey = __float_as_uint(judge) - OFFC;

    // the wave's two queries (from sorted array; bit-identical coords)
    const float4 q0 = sb[qslot + 0];
    const float4 q1 = sb[qslot + 1];
    const unsigned n0 = __float_as_uint(q0.w);
    const unsigned n1 = __float_as_uint(q1.w);

    // seed this wave's 16 slots (same-wave DS ops are in-order: seeds land
    // before any later atomic from this wave; no other wave touches them)
    unsigned long long* wsb = s_sb + wid * (QPW * 8);
    if (sub < 8)       wsb[sub]     = ((unsigned long long)seedkey << 32) | n0;
    else if (sub < 16) wsb[sub]     = ((unsigned long long)seedkey << 32) | n1;

    // shared candidate box: cells overlapping union of [q-r, q+r]
    const int lx = max(0, (int)((fminf(q0.x, q1.x) - r) * 4.0f));
    const int hx = min(3, (int)((fmaxf(q0.x, q1.x) + r) * 4.0f));
    const int ly = max(0, (int)((fminf(q0.y, q1.y) - r) * 4.0f));
    const int hy = min(3, (int)((fmaxf(q0.y, q1.y) + r) * 4.0f));
    const int lz = max(0, (int)((fminf(q0.z, q1.z) - r) * 4.0f));
    const int hz = min(3, (int)((fmaxf(q0.z, q1.z) + r) * 4.0f));

    __syncthreads();                             // s_off ready

    for (int cx = lx; cx <= hx; ++cx) {
        for (int cy = ly; cy <= hy; ++cy) {
            const int cb = (cx << 4) | (cy << 2);
            const int s = s_off[cb + lz];
            const int e = s_off[cb + hz + 1];    // cz-contiguous run
            #pragma unroll 4
            for (int p = s + sub; p < e; p += 64) {
                float4 c = sb[p];
                const unsigned long long ci =
                    (unsigned long long)__float_as_uint(c.w);
                // ---- query 0 ----
                {
                    float dx = __fsub_rn(c.x, q0.x);
                    float dy = __fsub_rn(c.y, q0.y);
                    float dz = __fsub_rn(c.z, q0.z);
                    float dist = __fadd_rn(__fadd_rn(__fmul_rn(dx, dx),
                                                     __fmul_rn(dy, dy)),
                                           __fmul_rn(dz, dz));
                    if (dist < judge) {
                        unsigned ikey = __float_as_uint(dist) - OFFC;
                        int code = (((int)__fadd_rn(dx, 1.0f)) * 4 +
                                    ((int)__fadd_rn(dy, 1.0f)) * 2 +
                                    ((int)__fadd_rn(dz, 1.0f)));
                        atomicMin(&wsb[code],
                                  ((unsigned long long)ikey << 32) | ci);
                    }
                }
                // ---- query 1 ----
                {
                    float dx = __fsub_rn(c.x, q1.x);
                    float dy = __fsub_rn(c.y, q1.y);
                    float dz = __fsub_rn(c.z, q1.z);
                    float dist = __fadd_rn(__fadd_rn(__fmul_rn(dx, dx),
                                                     __fmul_rn(dy, dy)),
                                           __fmul_rn(dz, dz));
                    if (dist < judge) {
                        unsigned ikey = __float_as_uint(dist) - OFFC;
                        int code = (((int)__fadd_rn(dx, 1.0f)) * 4 +
                                    ((int)__fadd_rn(dy, 1.0f)) * 2 +
                                    ((int)__fadd_rn(dz, 1.0f)));
                        atomicMin(&wsb[8 + code],
                                  ((unsigned long long)ikey << 32) | ci);
                    }
                }
            }
        }
    }

    // ---- fused epilogue: this wave writes both queries' entire output ----
    const float* xb = xyz + (size_t)b * NN * 3;
    const float* pb = points + (size_t)b * NN * CC;
    #pragma unroll
    for (int qq = 0; qq < QPW; ++qq) {
        const unsigned n = qq ? n1 : n0;
        const float4 q = qq ? q1 : q0;
        // winners: broadcast reads of the wave's slots (in-order after our
        // own atomics; no cross-wave sharing)
        unsigned idx8[8];
        #pragma unroll
        for (int o = 0; o < 8; ++o)
            idx8[o] = (unsigned)(wsb[qq * 8 + o] & 0xFFFFFFFFull);

        const size_t tb = ((size_t)b * NN + n) * 8;
        if (sub < 8)
            out[OUT2_OFF + tb + sub] = (float)idx8[sub];

        const float qc = (sub == 0) ? q.x : ((sub == 1) ? q.y : q.z);
        #pragma unroll
        for (int o = 0; o < 8; ++o) {
            const int i = (int)idx8[o];                      // wave-uniform
            const size_t t = tb + o;
            float v;
            if (sub < 3) v = __fsub_rn(xb[i * 3 + sub], qc);
            else         v = pb[(size_t)i * CC + (sub - 3)];
            __builtin_nontemporal_store(v, &out[OUT1_OFF + t * 67 + sub]);
            if (sub >= 61)                                   // ch 64..66
                __builtin_nontemporal_store(pb[(size_t)i * CC + sub],
                                            &out[OUT1_OFF + t * 67 + (sub + 3)]);
            if (sub < 3)
                __builtin_nontemporal_store(v, &out[OUT0_OFF + t * 3 + sub]);
        }
    }
}

extern "C" void kernel_launch(void* const* d_in, const int* in_sizes, int n_in,
                              void* d_out, int out_size, void* d_ws, size_t ws_size,
                              hipStream_t stream) {
    const float* xyz    = (const float*)d_in[0];
    const float* points = (const float*)d_in[1];
    const float* radius = (const float*)d_in[2];
    float* out = (float*)d_out;
    float4* ws_sorted = (float4*)d_ws;
    int* ws_offsets = (int*)((char*)d_ws + WS_SORTED_BYTES);

    // 1: counting-sort into 4x4x4 cells (one block per batch)
    hipLaunchKernelGGL(build_grid, dim3(BB), dim3(1024), 0, stream,
                       xyz, ws_sorted, ws_offsets);
    // 2: pruned octant select (2 queries/wave) + fused gather (1024 blocks)
    hipLaunchKernelGGL(select_gather,
                       dim3(BB * (NN / (4 * QPW))), dim3(NT), 0, stream,
                       ws_sorted, ws_offsets, xyz, points, radius, out);
}